// Round 1
// baseline (1184.964 us; speedup 1.0000x reference)
//
#include <hip/hip_runtime.h>
#include <hip/hip_bf16.h>
#include <stdint.h>

using bf16 = __hip_bfloat16;
typedef __attribute__((ext_vector_type(8))) short  frag_ab;   // 8 bf16 (4 VGPRs)
typedef __attribute__((ext_vector_type(4))) float  frag_cd;   // 4 fp32

#define AS3(p)  ((__attribute__((address_space(3))) void*)(p))
#define AS1C(p) ((const __attribute__((address_space(1))) void*)(p))

static __device__ __forceinline__ float bf_to_f(unsigned short h) {
  union { unsigned u; float f; } c; c.u = ((unsigned)h) << 16; return c.f;
}
static __device__ __forceinline__ unsigned short f_to_bf(float f) {
  union { float fv; unsigned u; } c; c.fv = f;
  unsigned u = c.u + (0x7FFFu + ((c.u >> 16) & 1u));   // round-to-nearest-even
  return (unsigned short)(u >> 16);
}

// ---- transpose + cast: out[c][r] = bf16(in[r][c]); in: RxC fp32, out: CxR bf16
// grid (C/32, R/32), block (32,8)
__global__ void transpose_cast_kernel(const float* __restrict__ in,
                                      unsigned short* __restrict__ out,
                                      int R, int C) {
  __shared__ float tile[32][33];
  const int c0 = blockIdx.x * 32;
  const int r0 = blockIdx.y * 32;
  const int tx = threadIdx.x, ty = threadIdx.y;
  #pragma unroll
  for (int i = 0; i < 32; i += 8)
    tile[ty + i][tx] = in[(size_t)(r0 + ty + i) * C + (c0 + tx)];
  __syncthreads();
  #pragma unroll
  for (int i = 0; i < 32; i += 8)
    out[(size_t)(c0 + ty + i) * R + (r0 + tx)] = f_to_bf(tile[tx][ty + i]);
}

// ---- elementwise cast fp32 -> bf16, 8 elems/thread
__global__ void cast_kernel(const float* __restrict__ in, unsigned short* __restrict__ out) {
  const size_t i = ((size_t)blockIdx.x * 256 + threadIdx.x) * 8;
  const float4 a = *(const float4*)(in + i);
  const float4 b = *(const float4*)(in + i + 4);
  frag_ab o;
  o[0] = (short)f_to_bf(a.x); o[1] = (short)f_to_bf(a.y);
  o[2] = (short)f_to_bf(a.z); o[3] = (short)f_to_bf(a.w);
  o[4] = (short)f_to_bf(b.x); o[5] = (short)f_to_bf(b.y);
  o[6] = (short)f_to_bf(b.z); o[7] = (short)f_to_bf(b.w);
  *(frag_ab*)(out + i) = o;
}

// ---- GEMM: C[m][n] = scale * sum_k A[m][k]*B[n][k]
// A: MxK bf16 row-major (k contiguous), B: NxK bf16, C: MxN (bf16 or fp32)
// block 256 (4 waves, 2x2), 128x128 tile, BK=32; grid (N/128, M/128). m97 structure.
template <bool OUT_BF16>
__global__ __launch_bounds__(256)
void gemm_tn_kernel(const bf16* __restrict__ A, const bf16* __restrict__ B,
                    void* __restrict__ Cv, int N, int K, float scale) {
  __shared__ __align__(16) bf16 lA[128 * 32];
  __shared__ __align__(16) bf16 lB[128 * 32];
  const int tid  = threadIdx.x;
  const int lane = tid & 63;
  const int wv   = tid >> 6;
  const int wr   = (wv >> 1) << 6;   // wave row offset (0/64)
  const int wc   = (wv & 1) << 6;    // wave col offset (0/64)
  const size_t bm = (size_t)blockIdx.y * 128;
  const size_t bn = (size_t)blockIdx.x * 128;

  frag_cd acc[4][4];
  #pragma unroll
  for (int i = 0; i < 4; ++i)
    #pragma unroll
    for (int j = 0; j < 4; ++j)
      acc[i][j] = (frag_cd){0.f, 0.f, 0.f, 0.f};

  // staging: tile = 128 rows x 32 cols; 512 16B-chunks; 2 per thread per operand.
  // chunk c -> row c>>2, colblock c&3 ; LDS elem offset c*8 (wave-uniform base + lane*16B)
  const int c0 = tid, c1 = tid + 256;
  const bf16* gA0 = A + (bm + (size_t)(c0 >> 2)) * K + (c0 & 3) * 8;
  const bf16* gA1 = A + (bm + (size_t)(c1 >> 2)) * K + (c1 & 3) * 8;
  const bf16* gB0 = B + (bn + (size_t)(c0 >> 2)) * K + (c0 & 3) * 8;
  const bf16* gB1 = B + (bn + (size_t)(c1 >> 2)) * K + (c1 & 3) * 8;
  bf16* const sA0 = lA + c0 * 8;
  bf16* const sA1 = lA + c1 * 8;
  bf16* const sB0 = lB + c0 * 8;
  bf16* const sB1 = lB + c1 * 8;

  const int mf = lane & 15;          // m/n within 16-tile
  const int kq = (lane >> 4) * 8;    // k offset for this quad

  for (int kt = 0; kt < K; kt += 32) {
    __syncthreads();  // previous iter's ds_reads done before overwrite
    __builtin_amdgcn_global_load_lds(AS1C(gA0 + kt), AS3(sA0), 16, 0, 0);
    __builtin_amdgcn_global_load_lds(AS1C(gA1 + kt), AS3(sA1), 16, 0, 0);
    __builtin_amdgcn_global_load_lds(AS1C(gB0 + kt), AS3(sB0), 16, 0, 0);
    __builtin_amdgcn_global_load_lds(AS1C(gB1 + kt), AS3(sB1), 16, 0, 0);
    __syncthreads();  // compiler emits vmcnt(0) drain before barrier

    frag_ab af[4], bfr[4];
    #pragma unroll
    for (int i = 0; i < 4; ++i) {
      af[i]  = *(const frag_ab*)(lA + (wr + i * 16 + mf) * 32 + kq);
      bfr[i] = *(const frag_ab*)(lB + (wc + i * 16 + mf) * 32 + kq);
    }
    #pragma unroll
    for (int mi = 0; mi < 4; ++mi)
      #pragma unroll
      for (int ni = 0; ni < 4; ++ni)
        acc[mi][ni] = __builtin_amdgcn_mfma_f32_16x16x32_bf16(af[mi], bfr[ni], acc[mi][ni], 0, 0, 0);
  }

  // C/D layout: col = lane&15, row = (lane>>4)*4 + reg (m89-verified)
  const int col = lane & 15;
  const int rq  = (lane >> 4) * 4;
  #pragma unroll
  for (int mi = 0; mi < 4; ++mi) {
    #pragma unroll
    for (int r = 0; r < 4; ++r) {
      const size_t m = bm + wr + mi * 16 + rq + r;
      #pragma unroll
      for (int ni = 0; ni < 4; ++ni) {
        const size_t n = bn + wc + ni * 16 + col;
        const float v = acc[mi][ni][r] * scale;
        if (OUT_BF16) ((unsigned short*)Cv)[m * (size_t)N + n] = f_to_bf(v);
        else          ((float*)Cv)[m * (size_t)N + n] = v;
      }
    }
  }
}

// ---- in-place row softmax over 8192 bf16 cols; one block (256 thr) per row
__global__ __launch_bounds__(256)
void softmax_kernel(unsigned short* __restrict__ S) {
  unsigned short* row = S + (size_t)blockIdx.x * 8192;
  const int tid = threadIdx.x;
  const int wv = tid >> 6, ln = tid & 63;
  __shared__ float red[8];

  float x[32];
  #pragma unroll
  for (int c = 0; c < 4; ++c) {
    frag_ab v = *(const frag_ab*)(row + c * 2048 + tid * 8);
    #pragma unroll
    for (int j = 0; j < 8; ++j) x[c * 8 + j] = bf_to_f((unsigned short)v[j]);
  }
  float mx = x[0];
  #pragma unroll
  for (int i = 1; i < 32; ++i) mx = fmaxf(mx, x[i]);
  #pragma unroll
  for (int off = 32; off >= 1; off >>= 1) mx = fmaxf(mx, __shfl_xor(mx, off, 64));
  if (ln == 0) red[wv] = mx;
  __syncthreads();
  mx = fmaxf(fmaxf(red[0], red[1]), fmaxf(red[2], red[3]));

  float s = 0.f;
  #pragma unroll
  for (int i = 0; i < 32; ++i) { x[i] = __expf(x[i] - mx); s += x[i]; }
  #pragma unroll
  for (int off = 32; off >= 1; off >>= 1) s += __shfl_xor(s, off, 64);
  if (ln == 0) red[4 + wv] = s;
  __syncthreads();
  const float inv = 1.f / ((red[4] + red[5]) + (red[6] + red[7]));

  #pragma unroll
  for (int c = 0; c < 4; ++c) {
    frag_ab o;
    #pragma unroll
    for (int j = 0; j < 8; ++j) o[j] = (short)f_to_bf(x[c * 8 + j] * inv);
    *(frag_ab*)(row + c * 2048 + tid * 8) = o;
  }
}

extern "C" void kernel_launch(void* const* d_in, const int* in_sizes, int n_in,
                              void* d_out, int out_size, void* d_ws, size_t ws_size,
                              hipStream_t stream) {
  const float* Q  = (const float*)d_in[0];  // (N=4096, QD=4096)
  const float* Km = (const float*)d_in[1];  // (N=4096, M=8192)
  const float* V  = (const float*)d_in[2];  // (VD=4096, M=8192)
  float* O = (float*)d_out;                 // (QD, VD) fp32

  const int Nc = 4096;   // contraction dim of gemm1 (rows of Q/K)
  const int QD = 4096;   // q_dim
  const int M  = 8192;   // keys
  const int VD = 4096;   // v_dim

  bf16* Qt = (bf16*)d_ws;                   // QD x Nc  (33.5 MB)
  bf16* Kt = Qt + (size_t)QD * Nc;          // M  x Nc  (67 MB)
  bf16* Vb = Kt + (size_t)M * Nc;           // VD x M   (67 MB)
  bf16* Sb = Vb + (size_t)VD * M;           // QD x M   (67 MB; softmax in-place)

  // Qt[i][n] = Q[n][i]; Kt[j][n] = K[n][j]  (k-contiguous operands for GEMM1)
  transpose_cast_kernel<<<dim3(QD / 32, Nc / 32), dim3(32, 8), 0, stream>>>(
      Q, (unsigned short*)Qt, Nc, QD);
  transpose_cast_kernel<<<dim3(M / 32, Nc / 32), dim3(32, 8), 0, stream>>>(
      Km, (unsigned short*)Kt, Nc, M);
  cast_kernel<<<(int)(((size_t)VD * M) / (256 * 8)), 256, 0, stream>>>(
      V, (unsigned short*)Vb);

  // S = (Qt @ Kt^T)/64 : (QD, M) bf16
  gemm_tn_kernel<true><<<dim3(M / 128, QD / 128), 256, 0, stream>>>(
      Qt, Kt, (void*)Sb, M, Nc, 0.015625f);
  // P = softmax(S) in-place
  softmax_kernel<<<QD, 256, 0, stream>>>((unsigned short*)Sb);
  // O = P @ Vb^T : (QD, VD) fp32
  gemm_tn_kernel<false><<<dim3(VD / 128, QD / 128), 256, 0, stream>>>(
      Sb, Vb, (void*)O, VD, M, 1.0f);
}

// Round 2
// 1137.211 us; speedup vs baseline: 1.0420x; 1.0420x over previous
//
#include <hip/hip_runtime.h>
#include <hip/hip_bf16.h>
#include <stdint.h>

using bf16 = __hip_bfloat16;
typedef __attribute__((ext_vector_type(8))) short  frag_ab;   // 8 bf16 (4 VGPRs)
typedef __attribute__((ext_vector_type(4))) float  frag_cd;   // 4 fp32

#define AS3(p)  ((__attribute__((address_space(3))) void*)(p))
#define AS1C(p) ((const __attribute__((address_space(1))) void*)(p))

static __device__ __forceinline__ float bf_to_f(unsigned short h) {
  union { unsigned u; float f; } c; c.u = ((unsigned)h) << 16; return c.f;
}
static __device__ __forceinline__ unsigned short f_to_bf(float f) {
  union { float fv; unsigned u; } c; c.fv = f;
  unsigned u = c.u + (0x7FFFu + ((c.u >> 16) & 1u));   // round-to-nearest-even
  return (unsigned short)(u >> 16);
}

// ---- transpose + cast: out[c][r] = bf16(in[r][c]); in: RxC fp32, out: CxR bf16
// grid (C/32, R/32), block (32,8)
__global__ void transpose_cast_kernel(const float* __restrict__ in,
                                      unsigned short* __restrict__ out,
                                      int R, int C) {
  __shared__ float tile[32][33];
  const int c0 = blockIdx.x * 32;
  const int r0 = blockIdx.y * 32;
  const int tx = threadIdx.x, ty = threadIdx.y;
  #pragma unroll
  for (int i = 0; i < 32; i += 8)
    tile[ty + i][tx] = in[(size_t)(r0 + ty + i) * C + (c0 + tx)];
  __syncthreads();
  #pragma unroll
  for (int i = 0; i < 32; i += 8)
    out[(size_t)(c0 + ty + i) * R + (r0 + tx)] = f_to_bf(tile[tx][ty + i]);
}

// ---- elementwise cast fp32 -> bf16, 8 elems/thread
__global__ void cast_kernel(const float* __restrict__ in, unsigned short* __restrict__ out) {
  const size_t i = ((size_t)blockIdx.x * 256 + threadIdx.x) * 8;
  const float4 a = *(const float4*)(in + i);
  const float4 b = *(const float4*)(in + i + 4);
  frag_ab o;
  o[0] = (short)f_to_bf(a.x); o[1] = (short)f_to_bf(a.y);
  o[2] = (short)f_to_bf(a.z); o[3] = (short)f_to_bf(a.w);
  o[4] = (short)f_to_bf(b.x); o[5] = (short)f_to_bf(b.y);
  o[6] = (short)f_to_bf(b.z); o[7] = (short)f_to_bf(b.w);
  *(frag_ab*)(out + i) = o;
}

// ---- GEMM: C[m][n] = scale * sum_k A[m][k]*B[n][k]
// A: MxK bf16 row-major (k contiguous), B: NxK bf16, C: MxN (bf16 or fp32)
// block 256 (4 waves, 2x2), 128x128 tile, BK=32; grid (N/128, M/128).
// LDS XOR swizzle at 16B granularity: chunk(row, cb) lives at 16B-pos
// row*4 + (cb ^ ((row>>1)&3)) -> every ds_read_b128 8-lane phase hits all 8
// four-bank groups (conflict-free); global_load_lds side implements the
// swizzle by permuting which global chunk each lane fetches (coalescing kept).
template <bool OUT_BF16>
__global__ __launch_bounds__(256)
void gemm_tn_kernel(const bf16* __restrict__ A, const bf16* __restrict__ B,
                    void* __restrict__ Cv, int N, int K, float scale) {
  __shared__ __align__(16) bf16 lA[128 * 32];
  __shared__ __align__(16) bf16 lB[128 * 32];
  const int tid  = threadIdx.x;
  const int lane = tid & 63;
  const int wv   = tid >> 6;
  const int wr   = (wv >> 1) << 6;   // wave row offset (0/64)
  const int wc   = (wv & 1) << 6;    // wave col offset (0/64)
  const size_t bm = (size_t)blockIdx.y * 128;
  const size_t bn = (size_t)blockIdx.x * 128;

  frag_cd acc[4][4];
  #pragma unroll
  for (int i = 0; i < 4; ++i)
    #pragma unroll
    for (int j = 0; j < 4; ++j)
      acc[i][j] = (frag_cd){0.f, 0.f, 0.f, 0.f};

  // staging: 512 16B-chunks per operand; LDS pos p gets global chunk
  // (r = p>>2, cb = (p&3) ^ ((r>>1)&3))  [inverse of the store swizzle]
  const int p0 = tid, p1 = tid + 256;
  const int r0c = p0 >> 2, r1c = p1 >> 2;
  const int cb0 = (p0 & 3) ^ ((r0c >> 1) & 3);
  const int cb1 = (p1 & 3) ^ ((r1c >> 1) & 3);
  const bf16* gA0 = A + (bm + (size_t)r0c) * K + cb0 * 8;
  const bf16* gA1 = A + (bm + (size_t)r1c) * K + cb1 * 8;
  const bf16* gB0 = B + (bn + (size_t)r0c) * K + cb0 * 8;
  const bf16* gB1 = B + (bn + (size_t)r1c) * K + cb1 * 8;
  bf16* const sA0 = lA + p0 * 8;
  bf16* const sA1 = lA + p1 * 8;
  bf16* const sB0 = lB + p0 * 8;
  bf16* const sB1 = lB + p1 * 8;

  const int mf   = lane & 15;        // m/n within 16-tile
  const int quad = lane >> 4;        // k quad (one 16B colblock)
  const int cbr  = quad ^ ((mf >> 1) & 3);   // swizzled colblock for reads

  for (int kt = 0; kt < K; kt += 32) {
    __syncthreads();  // previous iter's ds_reads done before overwrite
    __builtin_amdgcn_global_load_lds(AS1C(gA0 + kt), AS3(sA0), 16, 0, 0);
    __builtin_amdgcn_global_load_lds(AS1C(gA1 + kt), AS3(sA1), 16, 0, 0);
    __builtin_amdgcn_global_load_lds(AS1C(gB0 + kt), AS3(sB0), 16, 0, 0);
    __builtin_amdgcn_global_load_lds(AS1C(gB1 + kt), AS3(sB1), 16, 0, 0);
    __syncthreads();  // compiler emits vmcnt(0) drain before barrier

    frag_ab af[4], bfr[4];
    #pragma unroll
    for (int i = 0; i < 4; ++i) {
      af[i]  = *(const frag_ab*)(lA + ((wr + i * 16 + mf) * 4 + cbr) * 8);
      bfr[i] = *(const frag_ab*)(lB + ((wc + i * 16 + mf) * 4 + cbr) * 8);
    }
    #pragma unroll
    for (int mi = 0; mi < 4; ++mi)
      #pragma unroll
      for (int ni = 0; ni < 4; ++ni)
        acc[mi][ni] = __builtin_amdgcn_mfma_f32_16x16x32_bf16(af[mi], bfr[ni], acc[mi][ni], 0, 0, 0);
  }

  // C/D layout: col = lane&15, row = (lane>>4)*4 + reg (m89-verified)
  const int col = lane & 15;
  const int rq  = (lane >> 4) * 4;
  #pragma unroll
  for (int mi = 0; mi < 4; ++mi) {
    #pragma unroll
    for (int r = 0; r < 4; ++r) {
      const size_t m = bm + wr + mi * 16 + rq + r;
      #pragma unroll
      for (int ni = 0; ni < 4; ++ni) {
        const size_t n = bn + wc + ni * 16 + col;
        const float v = acc[mi][ni][r] * scale;
        if (OUT_BF16) ((unsigned short*)Cv)[m * (size_t)N + n] = f_to_bf(v);
        else          ((float*)Cv)[m * (size_t)N + n] = v;
      }
    }
  }
}

// ---- in-place row softmax over 8192 bf16 cols; one block (256 thr) per row
__global__ __launch_bounds__(256)
void softmax_kernel(unsigned short* __restrict__ S) {
  unsigned short* row = S + (size_t)blockIdx.x * 8192;
  const int tid = threadIdx.x;
  const int wv = tid >> 6, ln = tid & 63;
  __shared__ float red[8];

  float x[32];
  #pragma unroll
  for (int c = 0; c < 4; ++c) {
    frag_ab v = *(const frag_ab*)(row + c * 2048 + tid * 8);
    #pragma unroll
    for (int j = 0; j < 8; ++j) x[c * 8 + j] = bf_to_f((unsigned short)v[j]);
  }
  float mx = x[0];
  #pragma unroll
  for (int i = 1; i < 32; ++i) mx = fmaxf(mx, x[i]);
  #pragma unroll
  for (int off = 32; off >= 1; off >>= 1) mx = fmaxf(mx, __shfl_xor(mx, off, 64));
  if (ln == 0) red[wv] = mx;
  __syncthreads();
  mx = fmaxf(fmaxf(red[0], red[1]), fmaxf(red[2], red[3]));

  float s = 0.f;
  #pragma unroll
  for (int i = 0; i < 32; ++i) { x[i] = __expf(x[i] - mx); s += x[i]; }
  #pragma unroll
  for (int off = 32; off >= 1; off >>= 1) s += __shfl_xor(s, off, 64);
  if (ln == 0) red[4 + wv] = s;
  __syncthreads();
  const float inv = 1.f / ((red[4] + red[5]) + (red[6] + red[7]));

  #pragma unroll
  for (int c = 0; c < 4; ++c) {
    frag_ab o;
    #pragma unroll
    for (int j = 0; j < 8; ++j) o[j] = (short)f_to_bf(x[c * 8 + j] * inv);
    *(frag_ab*)(row + c * 2048 + tid * 8) = o;
  }
}

extern "C" void kernel_launch(void* const* d_in, const int* in_sizes, int n_in,
                              void* d_out, int out_size, void* d_ws, size_t ws_size,
                              hipStream_t stream) {
  const float* Q  = (const float*)d_in[0];  // (N=4096, QD=4096)
  const float* Km = (const float*)d_in[1];  // (N=4096, M=8192)
  const float* V  = (const float*)d_in[2];  // (VD=4096, M=8192)
  float* O = (float*)d_out;                 // (QD, VD) fp32

  const int Nc = 4096;   // contraction dim of gemm1 (rows of Q/K)
  const int QD = 4096;   // q_dim
  const int M  = 8192;   // keys
  const int VD = 4096;   // v_dim

  bf16* Qt = (bf16*)d_ws;                   // QD x Nc  (33.5 MB)
  bf16* Kt = Qt + (size_t)QD * Nc;          // M  x Nc  (67 MB)
  bf16* Vb = Kt + (size_t)M * Nc;           // VD x M   (67 MB)
  bf16* Sb = Vb + (size_t)VD * M;           // QD x M   (67 MB; softmax in-place)

  // Qt[i][n] = Q[n][i]; Kt[j][n] = K[n][j]  (k-contiguous operands for GEMM1)
  transpose_cast_kernel<<<dim3(QD / 32, Nc / 32), dim3(32, 8), 0, stream>>>(
      Q, (unsigned short*)Qt, Nc, QD);
  transpose_cast_kernel<<<dim3(M / 32, Nc / 32), dim3(32, 8), 0, stream>>>(
      Km, (unsigned short*)Kt, Nc, M);
  cast_kernel<<<(int)(((size_t)VD * M) / (256 * 8)), 256, 0, stream>>>(
      V, (unsigned short*)Vb);

  // S = (Qt @ Kt^T)/64 : (QD, M) bf16
  gemm_tn_kernel<true><<<dim3(M / 128, QD / 128), 256, 0, stream>>>(
      Qt, Kt, (void*)Sb, M, Nc, 0.015625f);
  // P = softmax(S) in-place
  softmax_kernel<<<QD, 256, 0, stream>>>((unsigned short*)Sb);
  // O = P @ Vb^T : (QD, VD) fp32
  gemm_tn_kernel<false><<<dim3(VD / 128, QD / 128), 256, 0, stream>>>(
      Sb, Vb, (void*)O, VD, M, 1.0f);
}

// Round 3
// 1112.844 us; speedup vs baseline: 1.0648x; 1.0219x over previous
//
#include <hip/hip_runtime.h>
#include <hip/hip_bf16.h>
#include <stdint.h>

using bf16 = __hip_bfloat16;
typedef __attribute__((ext_vector_type(8))) short  frag_ab;   // 8 bf16 (4 VGPRs)
typedef __attribute__((ext_vector_type(4))) float  frag_cd;   // 4 fp32

#define AS3(p)  ((__attribute__((address_space(3))) void*)(p))
#define AS1C(p) ((const __attribute__((address_space(1))) void*)(p))

static __device__ __forceinline__ float bf_to_f(unsigned short h) {
  union { unsigned u; float f; } c; c.u = ((unsigned)h) << 16; return c.f;
}
static __device__ __forceinline__ unsigned short f_to_bf(float f) {
  union { float fv; unsigned u; } c; c.fv = f;
  unsigned u = c.u + (0x7FFFu + ((c.u >> 16) & 1u));   // round-to-nearest-even
  return (unsigned short)(u >> 16);
}

// ---- transpose + cast: out[c][r] = bf16(in[r][c]); in: RxC fp32, out: CxR bf16
// 64x64 tile, 256 threads. 16B global loads (float4) and 16B global stores
// (8 x bf16). fp32 LDS tile, ld=65: both access phases are 2-way bank
// aliasing = free (m136). grid (C/64, R/64).
__global__ __launch_bounds__(256)
void transpose_cast_kernel(const float* __restrict__ in,
                           unsigned short* __restrict__ out,
                           int R, int C) {
  __shared__ float tile[64][65];
  const int t = threadIdx.x;
  const size_t c0 = (size_t)blockIdx.x * 64;
  const size_t r0 = (size_t)blockIdx.y * 64;
  const int lr = t >> 4;            // 0..15
  const int lc = (t & 15) * 4;      // 0..60
  #pragma unroll
  for (int i = 0; i < 64; i += 16) {
    const float4 v = *(const float4*)(in + (r0 + lr + i) * C + (c0 + lc));
    tile[lr + i][lc]     = v.x;
    tile[lr + i][lc + 1] = v.y;
    tile[lr + i][lc + 2] = v.z;
    tile[lr + i][lc + 3] = v.w;
  }
  __syncthreads();
  const int oc = t >> 3;            // 0..31
  const int orr = (t & 7) * 8;      // 0..56
  #pragma unroll
  for (int p = 0; p < 2; ++p) {
    const int c = oc + p * 32;
    frag_ab o;
    #pragma unroll
    for (int j = 0; j < 8; ++j) o[j] = (short)f_to_bf(tile[orr + j][c]);
    *(frag_ab*)(out + (c0 + c) * R + (r0 + orr)) = o;
  }
}

// ---- elementwise cast fp32 -> bf16, 8 elems/thread
__global__ void cast_kernel(const float* __restrict__ in, unsigned short* __restrict__ out) {
  const size_t i = ((size_t)blockIdx.x * 256 + threadIdx.x) * 8;
  const float4 a = *(const float4*)(in + i);
  const float4 b = *(const float4*)(in + i + 4);
  frag_ab o;
  o[0] = (short)f_to_bf(a.x); o[1] = (short)f_to_bf(a.y);
  o[2] = (short)f_to_bf(a.z); o[3] = (short)f_to_bf(a.w);
  o[4] = (short)f_to_bf(b.x); o[5] = (short)f_to_bf(b.y);
  o[6] = (short)f_to_bf(b.z); o[7] = (short)f_to_bf(b.w);
  *(frag_ab*)(out + i) = o;
}

// ---- GEMM: C[m][n] = scale * sum_k A[m][k]*B[n][k]
// A: MxK bf16 row-major (k contiguous), B: NxK bf16, C: MxN (bf16 or fp32)
// block 256 (4 waves, 2x2), 128x128 tile, BK=32; 1D grid = (N/128)*(M/128).
// Block swizzle: dispatch round-robins XCDs (bid%8) -> give each XCD a
// contiguous tile range, then group-of-4-m walk inside so an XCD's L2 holds
// 4 A-tiles + the shared B-tile.
// LDS XOR swizzle at 16B granularity keeps ds_read_b128 conflict-free (R1).
template <bool OUT_BF16>
__global__ __launch_bounds__(256)
void gemm_tn_kernel(const bf16* __restrict__ A, const bf16* __restrict__ B,
                    void* __restrict__ Cv, int N, int K, float scale,
                    int nbx, int nby) {
  __shared__ __align__(16) bf16 lA[128 * 32];
  __shared__ __align__(16) bf16 lB[128 * 32];
  const int tid  = threadIdx.x;
  const int lane = tid & 63;
  const int wv   = tid >> 6;
  const int wr   = (wv >> 1) << 6;   // wave row offset (0/64)
  const int wc   = (wv & 1) << 6;    // wave col offset (0/64)

  // ---- block swizzle (bijective): XCD-contiguous, then group-m(4)
  const int nb   = nbx * nby;
  const int bid  = blockIdx.x;
  const int u    = (bid & 7) * (nb >> 3) + (bid >> 3);
  const int GM = 4;
  const int width = GM * nbx;
  const int gid = u / width;
  const int pm  = gid * GM + (u % GM);
  const int pn  = (u % width) / GM;
  const size_t bm = (size_t)pm * 128;
  const size_t bn = (size_t)pn * 128;

  frag_cd acc[4][4];
  #pragma unroll
  for (int i = 0; i < 4; ++i)
    #pragma unroll
    for (int j = 0; j < 4; ++j)
      acc[i][j] = (frag_cd){0.f, 0.f, 0.f, 0.f};

  // staging: 512 16B-chunks per operand; LDS pos p gets global chunk
  // (r = p>>2, cb = (p&3) ^ ((r>>1)&3))  [inverse of the store swizzle]
  const int p0 = tid, p1 = tid + 256;
  const int r0c = p0 >> 2, r1c = p1 >> 2;
  const int cb0 = (p0 & 3) ^ ((r0c >> 1) & 3);
  const int cb1 = (p1 & 3) ^ ((r1c >> 1) & 3);
  const bf16* gA0 = A + (bm + (size_t)r0c) * K + cb0 * 8;
  const bf16* gA1 = A + (bm + (size_t)r1c) * K + cb1 * 8;
  const bf16* gB0 = B + (bn + (size_t)r0c) * K + cb0 * 8;
  const bf16* gB1 = B + (bn + (size_t)r1c) * K + cb1 * 8;
  bf16* const sA0 = lA + p0 * 8;
  bf16* const sA1 = lA + p1 * 8;
  bf16* const sB0 = lB + p0 * 8;
  bf16* const sB1 = lB + p1 * 8;

  const int mf   = lane & 15;        // m/n within 16-tile
  const int quad = lane >> 4;        // k quad (one 16B colblock)
  const int cbr  = quad ^ ((mf >> 1) & 3);   // swizzled colblock for reads

  for (int kt = 0; kt < K; kt += 32) {
    __syncthreads();  // previous iter's ds_reads done before overwrite
    __builtin_amdgcn_global_load_lds(AS1C(gA0 + kt), AS3(sA0), 16, 0, 0);
    __builtin_amdgcn_global_load_lds(AS1C(gA1 + kt), AS3(sA1), 16, 0, 0);
    __builtin_amdgcn_global_load_lds(AS1C(gB0 + kt), AS3(sB0), 16, 0, 0);
    __builtin_amdgcn_global_load_lds(AS1C(gB1 + kt), AS3(sB1), 16, 0, 0);
    __syncthreads();  // compiler emits vmcnt(0) drain before barrier

    frag_ab af[4], bfr[4];
    #pragma unroll
    for (int i = 0; i < 4; ++i) {
      af[i]  = *(const frag_ab*)(lA + ((wr + i * 16 + mf) * 4 + cbr) * 8);
      bfr[i] = *(const frag_ab*)(lB + ((wc + i * 16 + mf) * 4 + cbr) * 8);
    }
    #pragma unroll
    for (int mi = 0; mi < 4; ++mi)
      #pragma unroll
      for (int ni = 0; ni < 4; ++ni)
        acc[mi][ni] = __builtin_amdgcn_mfma_f32_16x16x32_bf16(af[mi], bfr[ni], acc[mi][ni], 0, 0, 0);
  }

  // C/D layout: col = lane&15, row = (lane>>4)*4 + reg (m89-verified)
  const int col = lane & 15;
  const int rq  = (lane >> 4) * 4;
  #pragma unroll
  for (int mi = 0; mi < 4; ++mi) {
    #pragma unroll
    for (int r = 0; r < 4; ++r) {
      const size_t m = bm + wr + mi * 16 + rq + r;
      #pragma unroll
      for (int ni = 0; ni < 4; ++ni) {
        const size_t n = bn + wc + ni * 16 + col;
        const float v = acc[mi][ni][r] * scale;
        if (OUT_BF16) ((unsigned short*)Cv)[m * (size_t)N + n] = f_to_bf(v);
        else          ((float*)Cv)[m * (size_t)N + n] = v;
      }
    }
  }
}

// ---- in-place row softmax over 8192 bf16 cols; one block (256 thr) per row
__global__ __launch_bounds__(256)
void softmax_kernel(unsigned short* __restrict__ S) {
  unsigned short* row = S + (size_t)blockIdx.x * 8192;
  const int tid = threadIdx.x;
  const int wv = tid >> 6, ln = tid & 63;
  __shared__ float red[8];

  float x[32];
  #pragma unroll
  for (int c = 0; c < 4; ++c) {
    frag_ab v = *(const frag_ab*)(row + c * 2048 + tid * 8);
    #pragma unroll
    for (int j = 0; j < 8; ++j) x[c * 8 + j] = bf_to_f((unsigned short)v[j]);
  }
  float mx = x[0];
  #pragma unroll
  for (int i = 1; i < 32; ++i) mx = fmaxf(mx, x[i]);
  #pragma unroll
  for (int off = 32; off >= 1; off >>= 1) mx = fmaxf(mx, __shfl_xor(mx, off, 64));
  if (ln == 0) red[wv] = mx;
  __syncthreads();
  mx = fmaxf(fmaxf(red[0], red[1]), fmaxf(red[2], red[3]));

  float s = 0.f;
  #pragma unroll
  for (int i = 0; i < 32; ++i) { x[i] = __expf(x[i] - mx); s += x[i]; }
  #pragma unroll
  for (int off = 32; off >= 1; off >>= 1) s += __shfl_xor(s, off, 64);
  if (ln == 0) red[4 + wv] = s;
  __syncthreads();
  const float inv = 1.f / ((red[4] + red[5]) + (red[6] + red[7]));

  #pragma unroll
  for (int c = 0; c < 4; ++c) {
    frag_ab o;
    #pragma unroll
    for (int j = 0; j < 8; ++j) o[j] = (short)f_to_bf(x[c * 8 + j] * inv);
    *(frag_ab*)(row + c * 2048 + tid * 8) = o;
  }
}

extern "C" void kernel_launch(void* const* d_in, const int* in_sizes, int n_in,
                              void* d_out, int out_size, void* d_ws, size_t ws_size,
                              hipStream_t stream) {
  const float* Q  = (const float*)d_in[0];  // (N=4096, QD=4096)
  const float* Km = (const float*)d_in[1];  // (N=4096, M=8192)
  const float* V  = (const float*)d_in[2];  // (VD=4096, M=8192)
  float* O = (float*)d_out;                 // (QD, VD) fp32

  const int Nc = 4096;   // contraction dim of gemm1 (rows of Q/K)
  const int QD = 4096;   // q_dim
  const int M  = 8192;   // keys
  const int VD = 4096;   // v_dim

  bf16* Qt = (bf16*)d_ws;                   // QD x Nc  (33.5 MB)
  bf16* Kt = Qt + (size_t)QD * Nc;          // M  x Nc  (67 MB)
  bf16* Vb = Kt + (size_t)M * Nc;           // VD x M   (67 MB)
  bf16* Sb = Vb + (size_t)VD * M;           // QD x M   (67 MB; softmax in-place)

  // Qt[i][n] = Q[n][i]; Kt[j][n] = K[n][j]  (k-contiguous operands for GEMM1)
  transpose_cast_kernel<<<dim3(QD / 64, Nc / 64), 256, 0, stream>>>(
      Q, (unsigned short*)Qt, Nc, QD);
  transpose_cast_kernel<<<dim3(M / 64, Nc / 64), 256, 0, stream>>>(
      Km, (unsigned short*)Kt, Nc, M);
  cast_kernel<<<(int)(((size_t)VD * M) / (256 * 8)), 256, 0, stream>>>(
      V, (unsigned short*)Vb);

  // S = (Qt @ Kt^T)/64 : (QD, M) bf16
  gemm_tn_kernel<true><<<(M / 128) * (QD / 128), 256, 0, stream>>>(
      Qt, Kt, (void*)Sb, M, Nc, 0.015625f, M / 128, QD / 128);
  // P = softmax(S) in-place
  softmax_kernel<<<QD, 256, 0, stream>>>((unsigned short*)Sb);
  // O = P @ Vb^T : (QD, VD) fp32
  gemm_tn_kernel<false><<<(VD / 128) * (QD / 128), 256, 0, stream>>>(
      Sb, Vb, (void*)O, VD, M, 1.0f, VD / 128, QD / 128);
}